// Round 12
// baseline (386.377 us; speedup 1.0000x reference)
//
#include <hip/hip_runtime.h>
#include <hip/hip_bf16.h>

#define EPSBN 1e-5f
#define BCAP 12288      // entries per window bucket
#define CSRL_CAP 13312  // LDS csr staging cap
#define OVCAP 262144    // overflow entries
#define INS_CAP 24      // per-block per-bin LDS insert cap
#define INS_STRIDE 25   // LDS row stride (gcd(25,32)=1 -> bank spread)

#if defined(__has_builtin)
#if __has_builtin(__builtin_amdgcn_cvt_pk_f32_fp8) && __has_builtin(__builtin_amdgcn_cvt_pk_fp8_f32)
#define HAS_CVT_FP8 1
#endif
#endif

typedef float v2f_t __attribute__((ext_vector_type(2)));

__device__ inline float fp8_dec_byte(int b) {
    int s = (b >> 7) & 1, e = (b >> 3) & 15, m = b & 7;
    float v = (e == 0) ? ldexpf((float)m, -9) : ldexpf((float)(8 + m), e - 10);
    return s ? -v : v;
}
__device__ inline unsigned int fp8_enc(float x) {
    unsigned int u = __float_as_uint(x);
    unsigned int s = u >> 31;
    u &= 0x7fffffffu;
    float a = __uint_as_float(u);
    unsigned int code;
    if (a >= 0.015625f) {
        if (a > 448.0f) code = 0x7E;
        else {
            int exp = (int)(u >> 23) - 127;
            unsigned int mant = u & 0x7fffffu;
            unsigned int keep = mant >> 20;
            unsigned int rest = mant & 0xfffffu;
            code = ((unsigned int)(exp + 7) << 3) | keep;
            unsigned int rnd = (rest > 0x80000u) || (rest == 0x80000u && (code & 1));
            code += rnd;
            if (code > 0x7E) code = 0x7E;
        }
    } else {
        code = (unsigned int)(a * 512.0f + 0.5f);
    }
    return (s << 7) | code;
}

// ---------------- setup: zero tails + graph bounds + BN fold ----------------
__global__ void setup_kernel(int* __restrict__ tails, int ntail,
                             const int* __restrict__ batch, int* __restrict__ gstart,
                             int n, int g,
                             const float* __restrict__ conv0_b, const float* __restrict__ convs_b,
                             const float* __restrict__ gamma, const float* __restrict__ beta,
                             const float* __restrict__ mean, const float* __restrict__ var,
                             float* __restrict__ sc, float* __restrict__ sh) {
    int i = blockIdx.x * 256 + threadIdx.x;
    if (i < ntail * 32) tails[i] = 0;
    if (i < 384) {
        int l = i >> 7, f = i & 127;
        float bias = (l == 0) ? conv0_b[f] : convs_b[(l - 1) * 128 + f];
        float s = gamma[i] * rsqrtf(var[i] + EPSBN);
        sc[i] = s;
        sh[i] = fmaf(s, bias - mean[i], beta[i]);
    }
    if (i < n) {
        int b = batch[i];
        int bp = (i == 0) ? -1 : batch[i - 1];
        for (int q = bp + 1; q <= b; ++q) gstart[q] = i;
        if (i == n - 1) {
            for (int q = b + 1; q <= g; ++q) gstart[q] = n;
        }
    }
}

// ---------------- bucket edges by dst window (d>>8) via LDS staging ----------------
__launch_bounds__(256)
__global__ void bucket_kernel(const int* __restrict__ src, const int* __restrict__ dst,
                              unsigned int* __restrict__ buckets, int* __restrict__ tails,
                              unsigned int* __restrict__ ovf, int e, int nwq) {
    __shared__ unsigned int buf[256 * INS_STRIDE];
    __shared__ int cnt[256];
    __shared__ int basee[256];
    int t = threadIdx.x;
    cnt[t] = 0;
    __syncthreads();
    int c0 = blockIdx.x * 2048;
    int c1 = min(c0 + 2048, e);
    for (int i = c0 + t; i < c1; i += 256) {
        int d = dst[i];
        int bb = d >> 8;
        unsigned int val = (unsigned int)src[i] | ((unsigned int)d << 16);
        int pos = atomicAdd(&cnt[bb], 1);
        if (pos < INS_CAP) buf[bb * INS_STRIDE + pos] = val;
        else {
            int op = atomicAdd(&tails[nwq * 32], 1);
            if (op < OVCAP) ovf[op] = val;
        }
    }
    __syncthreads();
    int lane = t & 63, wv = t >> 6;
    int bb0 = wv * 64;
    {
        int b = bb0 + lane;
        int c = (b < nwq) ? min(cnt[b], INS_CAP) : 0;
        basee[b] = c ? atomicAdd(&tails[b * 32], c) : 0;
    }
    for (int k = 0; k < 64; ++k) {
        int b = bb0 + k;
        if (b >= nwq) break;
        int c = min(cnt[b], INS_CAP);
        if (c == 0) continue;
        int g = basee[b];
        if (lane < c) {
            unsigned int v = buf[b * INS_STRIDE + lane];
            int gp = g + lane;
            if (gp < BCAP) buckets[(size_t)b * BCAP + gp] = v;
            else {
                int op = atomicAdd(&tails[nwq * 32], 1);
                if (op < OVCAP) ovf[op] = v;
            }
        }
    }
}

// ---------------- build CSR window-locally in LDS; coalesced write-out ----------------
__launch_bounds__(256)
__global__ void build_csr(const unsigned int* __restrict__ buckets,
                          const int* __restrict__ tails, const unsigned int* __restrict__ ovf,
                          unsigned short* __restrict__ csr, int* __restrict__ deg,
                          int* __restrict__ offs, float* __restrict__ dinv,
                          int n, int nwq) {
    __shared__ unsigned short csrL[CSRL_CAP];
    __shared__ int degL[256], curL[256], offsL[256], cntW[256];
    __shared__ int wsum4[4];
    __shared__ int wstart;
    int b = blockIdx.x, t = threadIdx.x;
    int lo = b << 8;
    int hi = min(lo + 256, n);
    int nw = hi - lo;
    int ovn = min(tails[nwq * 32], OVCAP);
    cntW[t] = (t < nwq) ? min(tails[t * 32], BCAP) : 0;
    degL[t] = 0;
    __syncthreads();
    for (int i = t; i < ovn; i += 256)
        atomicAdd(&cntW[(ovf[i] >> 16) >> 8], 1);
    __syncthreads();
    if (t == 0) {
        int s = 0;
        for (int w = 0; w < b; ++w) s += cntW[w];
        wstart = s;
    }
    int myvalid = min(tails[b * 32], BCAP);
    const unsigned int* myb = buckets + (size_t)b * BCAP;
    for (int i = t; i < myvalid; i += 256)
        atomicAdd(&degL[(myb[i] >> 16) & 255], 1);
    for (int i = t; i < ovn; i += 256) {
        unsigned int v = ovf[i];
        int d = v >> 16;
        if (d >= lo && d < hi) atomicAdd(&degL[d & 255], 1);
    }
    __syncthreads();
    {
        int lane = t & 63, wv = t >> 6;
        int v = degL[t];
        int sc = v;
        #pragma unroll
        for (int o = 1; o < 64; o <<= 1) {
            int u = __shfl_up(sc, o);
            if (lane >= o) sc += u;
        }
        if (lane == 63) wsum4[wv] = sc;
        __syncthreads();
        int wb = 0;
        for (int q = 0; q < wv; ++q) wb += wsum4[q];
        offsL[t] = wb + sc - v;
        curL[t] = offsL[t];
    }
    __syncthreads();
    for (int i = t; i < myvalid; i += 256) {
        unsigned int v = myb[i];
        int pos = atomicAdd(&curL[(v >> 16) & 255], 1);
        if (pos < CSRL_CAP) csrL[pos] = (unsigned short)(v & 0xffffu);
    }
    for (int i = t; i < ovn; i += 256) {
        unsigned int v = ovf[i];
        int d = v >> 16;
        if (d >= lo && d < hi) {
            int pos = atomicAdd(&curL[d & 255], 1);
            if (pos < CSRL_CAP) csrL[pos] = (unsigned short)(v & 0xffffu);
        }
    }
    __syncthreads();
    int base = wstart;
    int total = min(cntW[b], CSRL_CAP);
    for (int i = t; i < total; i += 256)
        csr[base + i] = csrL[i];
    if (t < nw) {
        int dgi = degL[t];
        deg[lo + t] = dgi;
        offs[lo + t] = base + offsL[t];
        dinv[lo + t] = rsqrtf((float)dgi + 1.0f);
    }
}

// ---------------- GEMM phase (512 thr): LDS h-tile [64][132] @ W[128x128] -> fp8 out ----------------
__device__ inline void gemm_phase(const float* __restrict__ shtile, const float* __restrict__ W,
                                  unsigned char* __restrict__ out, int row0, int rows) {
    int t = threadIdx.x;              // 512 threads
    int f0 = (t & 15) * 8;
    int r0 = (t >> 4) * 2;            // 32 groups x 2 rows = 64 rows
    float acc[2][8];
    #pragma unroll
    for (int i = 0; i < 2; ++i)
        #pragma unroll
        for (int c = 0; c < 8; ++c) acc[i][c] = 0.f;

    for (int k0 = 0; k0 < 128; k0 += 4) {
        float a_s[2][4];
        #pragma unroll
        for (int i = 0; i < 2; ++i) {
            float4 v = *(const float4*)(&shtile[(r0 + i) * 132 + k0]);
            a_s[i][0] = v.x; a_s[i][1] = v.y; a_s[i][2] = v.z; a_s[i][3] = v.w;
        }
        float w_s[4][8];
        #pragma unroll
        for (int j = 0; j < 4; ++j) {
            float4 w0 = *(const float4*)(W + (size_t)(k0 + j) * 128 + f0);
            float4 w1 = *(const float4*)(W + (size_t)(k0 + j) * 128 + f0 + 4);
            w_s[j][0] = w0.x; w_s[j][1] = w0.y; w_s[j][2] = w0.z; w_s[j][3] = w0.w;
            w_s[j][4] = w1.x; w_s[j][5] = w1.y; w_s[j][6] = w1.z; w_s[j][7] = w1.w;
        }
        #pragma unroll
        for (int j = 0; j < 4; ++j)
            #pragma unroll
            for (int i = 0; i < 2; ++i)
                #pragma unroll
                for (int c = 0; c < 8; ++c)
                    acc[i][c] = fmaf(a_s[i][j], w_s[j][c], acc[i][c]);
    }

    #pragma unroll
    for (int i = 0; i < 2; ++i) {
        if (r0 + i < rows) {
            unsigned int q0, q1;
#ifdef HAS_CVT_FP8
            int p = __builtin_amdgcn_cvt_pk_fp8_f32(acc[i][0], acc[i][1], 0, false);
            p = __builtin_amdgcn_cvt_pk_fp8_f32(acc[i][2], acc[i][3], p, true);
            q0 = (unsigned int)p;
            int p2 = __builtin_amdgcn_cvt_pk_fp8_f32(acc[i][4], acc[i][5], 0, false);
            p2 = __builtin_amdgcn_cvt_pk_fp8_f32(acc[i][6], acc[i][7], p2, true);
            q1 = (unsigned int)p2;
#else
            q0 = fp8_enc(acc[i][0]) | (fp8_enc(acc[i][1]) << 8) |
                 (fp8_enc(acc[i][2]) << 16) | (fp8_enc(acc[i][3]) << 24);
            q1 = fp8_enc(acc[i][4]) | (fp8_enc(acc[i][5]) << 8) |
                 (fp8_enc(acc[i][6]) << 16) | (fp8_enc(acc[i][7]) << 24);
#endif
            uint2 o; o.x = q0; o.y = q1;
            *(uint2*)(out + (size_t)(row0 + r0 + i) * 128 + f0) = o;
        }
    }
}

// ---------------- fused layer0 + gemm1 (512 thr, 8 waves x 8 nodes) ----------------
__launch_bounds__(512)
__global__ void l0_gemm1(const float* __restrict__ x, const unsigned short* __restrict__ csr,
                         const int* __restrict__ offs, const int* __restrict__ degi,
                         const float* __restrict__ dinv, const float* __restrict__ W0,
                         const float* __restrict__ sc, const float* __restrict__ shv,
                         const float* __restrict__ W1, unsigned char* __restrict__ out, int n) {
    __shared__ float sh[64 * 132];
    __shared__ float sW[7 * 128];
    __shared__ float ssc[128], ssh[128];
    int t = threadIdx.x;
    for (int i = t; i < 7 * 128; i += 512) sW[i] = W0[i];
    if (t < 128) { ssc[t] = sc[t]; ssh[t] = shv[t]; }
    __syncthreads();
    int lane = t & 63, wv = t >> 6;     // 8 waves
    int row0 = blockIdx.x * 64;
    int e = lane >> 3, f = lane & 7;
    for (int it = 0; it < 8; ++it) {
        int row = wv + it * 8;
        int node = row0 + row;
        if (node < n) {
            int off = offs[node], cnt = degi[node];
            float di = dinv[node];
            float acc = 0.f, accB = 0.f;
            for (int b0 = 0; b0 < cnt; b0 += 64) {
                int j = b0 + lane;
                int s = 0; float dv = 0.f;
                if (j < cnt) { s = csr[off + j]; dv = dinv[s]; }
                int m = cnt - b0; if (m > 64) m = 64;
                int m16 = (m + 15) & ~15;
                for (int i2 = 0; i2 < m16; i2 += 16) {
                    int ss1 = __shfl(s, i2 + e);
                    int ss2 = __shfl(s, i2 + 8 + e);
                    float d1 = __shfl(dv, i2 + e);
                    float d2 = __shfl(dv, i2 + 8 + e);
                    float v1 = 0.f, v2 = 0.f;
                    if (f < 7) {
                        v1 = d1 * x[(size_t)ss1 * 7 + f];
                        v2 = d2 * x[(size_t)ss2 * 7 + f];
                    }
                    acc += v1; accB += v2;
                }
            }
            acc += accB;
            acc += __shfl_xor(acc, 8);
            acc += __shfl_xor(acc, 16);
            acc += __shfl_xor(acc, 32);
            float self = (f < 7) ? x[(size_t)node * 7 + f] : 0.f;
            float xa = di * (acc + di * self);
            float xk[7];
            #pragma unroll
            for (int k = 0; k < 7; ++k) xk[k] = __shfl(xa, k);
            int fo = lane * 2;
            float o0 = 0.f, o1 = 0.f;
            #pragma unroll
            for (int k = 0; k < 7; ++k) {
                o0 = fmaf(xk[k], sW[k * 128 + fo], o0);
                o1 = fmaf(xk[k], sW[k * 128 + fo + 1], o1);
            }
            o0 = fmaxf(fmaf(ssc[fo],     o0, ssh[fo]),     0.f);
            o1 = fmaxf(fmaf(ssc[fo + 1], o1, ssh[fo + 1]), 0.f);
            *(float2*)(&sh[row * 132 + fo]) = make_float2(o0, o1);
        }
    }
    __syncthreads();
    int rows = n - row0; if (rows > 64) rows = 64;
    gemm_phase(sh, W1, out, row0, rows);
}

// ---------------- fused agg1 + gemm2 (512 thr, 8 waves x 8 nodes) ----------------
__launch_bounds__(512)
__global__ void agg_gemm(const unsigned int* __restrict__ hw, const unsigned short* __restrict__ csr,
                         const int* __restrict__ offs, const int* __restrict__ degi,
                         const float* __restrict__ dinv,
                         const float* __restrict__ sc, const float* __restrict__ shv,
                         const float* __restrict__ W2, unsigned char* __restrict__ out, int n) {
    __shared__ float sh[64 * 132];
#ifndef HAS_CVT_FP8
    __shared__ float lut[256];
    if (threadIdx.x < 256) lut[threadIdx.x] = fp8_dec_byte(threadIdx.x);
    __syncthreads();
#endif
    int t = threadIdx.x;
    int lane = t & 63, wv = t >> 6;
    int fl = lane & 31, half = lane >> 5;
    int row0 = blockIdx.x * 64;
    for (int it = 0; it < 8; ++it) {
        int row = wv + it * 8;
        int node = row0 + row;
        if (node < n) {
            float di = dinv[node];
            float a0 = 0.f, a1 = 0.f, a2 = 0.f, a3 = 0.f;
            int off = offs[node], cnt = degi[node];
            for (int b0 = 0; b0 < cnt; b0 += 64) {
                int j = b0 + lane;
                int s = 0; float dv = 0.f;
                if (j < cnt) { s = csr[off + j]; dv = dinv[s]; }
                int m = cnt - b0; if (m > 64) m = 64;
                int m16 = (m + 15) & ~15;
                for (int e = 0; e < m16; e += 16) {
                    unsigned int w[8]; float nn[8];
                    #pragma unroll
                    for (int u = 0; u < 8; ++u) {
                        int jj = e + u * 2 + half;
                        int ss = __shfl(s, jj);
                        nn[u] = __shfl(dv, jj);
                        w[u] = hw[(size_t)ss * 32 + fl];
                    }
                    #pragma unroll
                    for (int u = 0; u < 8; ++u) {
#ifdef HAS_CVT_FP8
                        v2f_t lo = __builtin_amdgcn_cvt_pk_f32_fp8((int)w[u], false);
                        v2f_t hi = __builtin_amdgcn_cvt_pk_f32_fp8((int)w[u], true);
                        a0 = fmaf(nn[u], lo[0], a0);
                        a1 = fmaf(nn[u], lo[1], a1);
                        a2 = fmaf(nn[u], hi[0], a2);
                        a3 = fmaf(nn[u], hi[1], a3);
#else
                        a0 = fmaf(nn[u], lut[w[u] & 255], a0);
                        a1 = fmaf(nn[u], lut[(w[u] >> 8) & 255], a1);
                        a2 = fmaf(nn[u], lut[(w[u] >> 16) & 255], a2);
                        a3 = fmaf(nn[u], lut[w[u] >> 24], a3);
#endif
                    }
                }
            }
            a0 += __shfl_xor(a0, 32);
            a1 += __shfl_xor(a1, 32);
            a2 += __shfl_xor(a2, 32);
            a3 += __shfl_xor(a3, 32);
            if (half == 0) {
                int f0 = fl * 4;
                unsigned int ws = hw[(size_t)node * 32 + fl];
                float s0, s1, s2, s3;
#ifdef HAS_CVT_FP8
                v2f_t lo = __builtin_amdgcn_cvt_pk_f32_fp8((int)ws, false);
                v2f_t hi = __builtin_amdgcn_cvt_pk_f32_fp8((int)ws, true);
                s0 = lo[0]; s1 = lo[1]; s2 = hi[0]; s3 = hi[1];
#else
                s0 = lut[ws & 255]; s1 = lut[(ws >> 8) & 255];
                s2 = lut[(ws >> 16) & 255]; s3 = lut[ws >> 24];
#endif
                a0 = (a0 + di * s0) * di;
                a1 = (a1 + di * s1) * di;
                a2 = (a2 + di * s2) * di;
                a3 = (a3 + di * s3) * di;
                float4 o;
                o.x = fmaxf(fmaf(sc[f0],     a0, shv[f0]),     0.f);
                o.y = fmaxf(fmaf(sc[f0 + 1], a1, shv[f0 + 1]), 0.f);
                o.z = fmaxf(fmaf(sc[f0 + 2], a2, shv[f0 + 2]), 0.f);
                o.w = fmaxf(fmaf(sc[f0 + 3], a3, shv[f0 + 3]), 0.f);
                *(float4*)(&sh[row * 132 + f0]) = o;
            }
        }
    }
    __syncthreads();
    int rows = n - row0; if (rows > 64) rows = 64;
    gemm_phase(sh, W2, out, row0, rows);
}

// ---------------- final aggregation layer (standalone, fp32 out) ----------------
__launch_bounds__(256)
__global__ void agg_fp8(const unsigned int* __restrict__ hw, const unsigned short* __restrict__ csr,
                        const int* __restrict__ offs, const int* __restrict__ degi,
                        const float* __restrict__ dinv,
                        const float* __restrict__ sc, const float* __restrict__ shv,
                        float* __restrict__ out, int n) {
#ifndef HAS_CVT_FP8
    __shared__ float lut[256];
    if (threadIdx.x < 256) lut[threadIdx.x] = fp8_dec_byte(threadIdx.x);
    __syncthreads();
#endif
    int lane = threadIdx.x & 63;
    int node = blockIdx.x * 4 + (threadIdx.x >> 6);
    if (node >= n) return;
    int fl = lane & 31, half = lane >> 5;
    float di = dinv[node];
    float a0 = 0.f, a1 = 0.f, a2 = 0.f, a3 = 0.f;
    int off = offs[node], cnt = degi[node];

    for (int b0 = 0; b0 < cnt; b0 += 64) {
        int j = b0 + lane;
        int s = 0; float dv = 0.f;
        if (j < cnt) { s = csr[off + j]; dv = dinv[s]; }
        int m = cnt - b0; if (m > 64) m = 64;
        int m16 = (m + 15) & ~15;
        for (int e = 0; e < m16; e += 16) {
            unsigned int w[8]; float nn[8];
            #pragma unroll
            for (int u = 0; u < 8; ++u) {
                int jj = e + u * 2 + half;
                int ss = __shfl(s, jj);
                nn[u] = __shfl(dv, jj);
                w[u] = hw[(size_t)ss * 32 + fl];
            }
            #pragma unroll
            for (int u = 0; u < 8; ++u) {
#ifdef HAS_CVT_FP8
                v2f_t lo = __builtin_amdgcn_cvt_pk_f32_fp8((int)w[u], false);
                v2f_t hi = __builtin_amdgcn_cvt_pk_f32_fp8((int)w[u], true);
                a0 = fmaf(nn[u], lo[0], a0);
                a1 = fmaf(nn[u], lo[1], a1);
                a2 = fmaf(nn[u], hi[0], a2);
                a3 = fmaf(nn[u], hi[1], a3);
#else
                a0 = fmaf(nn[u], lut[w[u] & 255], a0);
                a1 = fmaf(nn[u], lut[(w[u] >> 8) & 255], a1);
                a2 = fmaf(nn[u], lut[(w[u] >> 16) & 255], a2);
                a3 = fmaf(nn[u], lut[w[u] >> 24], a3);
#endif
            }
        }
    }
    a0 += __shfl_xor(a0, 32);
    a1 += __shfl_xor(a1, 32);
    a2 += __shfl_xor(a2, 32);
    a3 += __shfl_xor(a3, 32);
    if (half == 0) {
        int f0 = fl * 4;
        unsigned int ws = hw[(size_t)node * 32 + fl];
        float s0, s1, s2, s3;
#ifdef HAS_CVT_FP8
        v2f_t lo = __builtin_amdgcn_cvt_pk_f32_fp8((int)ws, false);
        v2f_t hi = __builtin_amdgcn_cvt_pk_f32_fp8((int)ws, true);
        s0 = lo[0]; s1 = lo[1]; s2 = hi[0]; s3 = hi[1];
#else
        s0 = lut[ws & 255]; s1 = lut[(ws >> 8) & 255];
        s2 = lut[(ws >> 16) & 255]; s3 = lut[ws >> 24];
#endif
        a0 = (a0 + di * s0) * di;
        a1 = (a1 + di * s1) * di;
        a2 = (a2 + di * s2) * di;
        a3 = (a3 + di * s3) * di;
        float4 o;
        o.x = fmaxf(fmaf(sc[f0],     a0, shv[f0]),     0.f);
        o.y = fmaxf(fmaf(sc[f0 + 1], a1, shv[f0 + 1]), 0.f);
        o.z = fmaxf(fmaf(sc[f0 + 2], a2, shv[f0 + 2]), 0.f);
        o.w = fmaxf(fmaf(sc[f0 + 3], a3, shv[f0 + 3]), 0.f);
        *(float4*)(out + (size_t)node * 128 + f0) = o;
    }
}

// ---------------- pocket MLP + fold bilinear ----------------
__global__ void pk_bilM_kernel(const float* __restrict__ pf, const float* __restrict__ W1,
                               const float* __restrict__ b1, const float* __restrict__ W2,
                               const float* __restrict__ b2, const float* __restrict__ bilW,
                               float* __restrict__ M) {
    __shared__ float h1[64];
    __shared__ float spk[64];
    int t = threadIdx.x;
    if (t < 64) {
        float acc = b1[t];
        #pragma unroll
        for (int k = 0; k < 28; ++k) acc = fmaf(pf[k], W1[k * 64 + t], acc);
        h1[t] = fmaxf(acc, 0.f);
    }
    __syncthreads();
    if (t < 64) {
        float acc2 = b2[t];
        for (int k = 0; k < 64; ++k) acc2 = fmaf(h1[k], W2[k * 64 + t], acc2);
        spk[t] = acc2;
    }
    __syncthreads();
    int idx = blockIdx.x * 256 + t;
    if (idx < 64 * 128) {
        const float* wr = bilW + (size_t)idx * 64;
        float acc = 0.f;
        #pragma unroll 8
        for (int j = 0; j < 64; ++j) acc = fmaf(wr[j], spk[j], acc);
        M[idx] = acc;
    }
}

// ---------------- per-graph tail (fused segment-mean + bilinear + classifier) ----------------
__launch_bounds__(128)
__global__ void final_kernel(const float* __restrict__ h, const int* __restrict__ gstart,
                             const float* __restrict__ M, const float* __restrict__ bil_b,
                             const float* __restrict__ cW1, const float* __restrict__ cb1,
                             const float* __restrict__ cW2, const float* __restrict__ cb2,
                             float* __restrict__ out) {
    __shared__ float lig[128];
    __shared__ float inter[64];
    __shared__ float hc[32];
    int g = blockIdx.x, t = threadIdx.x;
    int s = gstart[g], e = gstart[g + 1];
    float a0 = 0.f, a1 = 0.f, a2 = 0.f, a3 = 0.f;
    int i = s;
    for (; i + 4 <= e; i += 4) {
        a0 += h[(size_t)(i + 0) * 128 + t];
        a1 += h[(size_t)(i + 1) * 128 + t];
        a2 += h[(size_t)(i + 2) * 128 + t];
        a3 += h[(size_t)(i + 3) * 128 + t];
    }
    for (; i < e; ++i) a0 += h[(size_t)i * 128 + t];
    float c = (float)(e - s); if (c < 1.f) c = 1.f;
    lig[t] = ((a0 + a1) + (a2 + a3)) / c;
    __syncthreads();
    if (t < 64) {
        float acc = bil_b[t];
        const float* mr = M + (size_t)t * 128;
        #pragma unroll 8
        for (int k = 0; k < 128; ++k) acc = fmaf(lig[k], mr[k], acc);
        inter[t] = acc;
    }
    __syncthreads();
    if (t < 32) {
        float acc = cb1[t];
        #pragma unroll 8
        for (int o = 0; o < 64; ++o) acc = fmaf(inter[o], cW1[o * 32 + t], acc);
        hc[t] = fmaxf(acc, 0.f);
    }
    __syncthreads();
    if (t == 0) {
        float acc = cb2[0];
        #pragma unroll
        for (int j = 0; j < 32; ++j) acc = fmaf(hc[j], cW2[j], acc);
        out[g] = acc;
    }
}

extern "C" void kernel_launch(void* const* d_in, const int* in_sizes, int n_in,
                              void* d_out, int out_size, void* d_ws, size_t ws_size,
                              hipStream_t stream) {
    const float* x        = (const float*)d_in[0];
    const int*   edge     = (const int*)d_in[1];
    const int*   batch    = (const int*)d_in[2];
    const float* pocket   = (const float*)d_in[3];
    const float* conv0_W  = (const float*)d_in[4];
    const float* conv0_b  = (const float*)d_in[5];
    const float* convs_W  = (const float*)d_in[6];
    const float* convs_b  = (const float*)d_in[7];
    const float* bn_gamma = (const float*)d_in[8];
    const float* bn_beta  = (const float*)d_in[9];
    const float* bn_mean  = (const float*)d_in[10];
    const float* bn_var   = (const float*)d_in[11];
    const float* pmlp_W1  = (const float*)d_in[12];
    const float* pmlp_b1  = (const float*)d_in[13];
    const float* pmlp_W2  = (const float*)d_in[14];
    const float* pmlp_b2  = (const float*)d_in[15];
    const float* bil_W    = (const float*)d_in[16];
    const float* bil_b    = (const float*)d_in[17];
    const float* cls_W1   = (const float*)d_in[18];
    const float* cls_b1   = (const float*)d_in[19];
    const float* cls_W2   = (const float*)d_in[20];
    const float* cls_b2   = (const float*)d_in[21];

    const int N = in_sizes[0] / 7;
    const int E = in_sizes[1] / 2;
    const int G = out_size;
    const int* srcA = edge;
    const int* dstA = edge + E;
    const int NB = (N + 255) / 256;
    const int NWQ = (N + 255) >> 8;

    char* p = (char*)d_ws;
    auto alloc = [&](size_t bytes) -> void* {
        void* r = (void*)p;
        p += (bytes + 255) & ~(size_t)255;
        return r;
    };
    int*   tails    = (int*)alloc((size_t)(NWQ + 1) * 32 * 4);
    unsigned int* buckets = (unsigned int*)alloc((size_t)NWQ * BCAP * 4);
    unsigned int* ovf     = (unsigned int*)alloc((size_t)OVCAP * 4);
    int*   deg      = (int*)alloc((size_t)N * 4);
    int*   offs     = (int*)alloc((size_t)N * 4);
    float* dinv     = (float*)alloc((size_t)N * 4);
    unsigned short* csr = (unsigned short*)alloc((size_t)E * 2);
    unsigned char* tab1 = (unsigned char*)alloc((size_t)N * 128);
    unsigned char* tab2 = (unsigned char*)alloc((size_t)N * 128);
    float* bufF     = (float*)alloc((size_t)N * 128 * 4);
    int*   gstart   = (int*)alloc((size_t)(G + 1) * 4);
    float* M        = (float*)alloc(64 * 128 * 4);
    float* sc       = (float*)alloc(384 * 4);
    float* shv      = (float*)alloc(384 * 4);

    setup_kernel<<<NB, 256, 0, stream>>>(tails, NWQ + 1, batch, gstart, N, G,
                                         conv0_b, convs_b, bn_gamma, bn_beta, bn_mean, bn_var,
                                         sc, shv);
    bucket_kernel<<<(E + 2047) / 2048, 256, 0, stream>>>(srcA, dstA, buckets, tails, ovf,
                                                         E, NWQ);
    build_csr<<<NWQ, 256, 0, stream>>>(buckets, tails, ovf, csr, deg, offs, dinv, N, NWQ);

    // layer0 + gemm1 fused -> fp8 table1
    l0_gemm1<<<(N + 63) / 64, 512, 0, stream>>>(x, csr, offs, deg, dinv, conv0_W,
                                                sc, shv, convs_W, tab1, N);
    // agg1 + gemm2 fused -> fp8 table2
    agg_gemm<<<(N + 63) / 64, 512, 0, stream>>>((const unsigned int*)tab1, csr, offs, deg, dinv,
                                                sc + 128, shv + 128, convs_W + 128 * 128,
                                                tab2, N);
    // agg2 -> fp32 node features
    agg_fp8<<<(N + 3) / 4, 256, 0, stream>>>((const unsigned int*)tab2, csr, offs, deg, dinv,
                                             sc + 256, shv + 256, bufF, N);

    pk_bilM_kernel<<<32, 256, 0, stream>>>(pocket, pmlp_W1, pmlp_b1, pmlp_W2, pmlp_b2,
                                           bil_W, M);
    final_kernel<<<G, 128, 0, stream>>>(bufF, gstart, M, bil_b, cls_W1, cls_b1, cls_W2, cls_b2,
                                        (float*)d_out);
}

// Round 13
// 344.088 us; speedup vs baseline: 1.1229x; 1.1229x over previous
//
#include <hip/hip_runtime.h>
#include <hip/hip_bf16.h>

#define EPSBN 1e-5f
#define BCAP 12288      // entries per window bucket
#define CSRL_CAP 13312  // LDS csr staging cap
#define OVCAP 262144    // overflow entries
#define INS_CAP 24      // per-block per-bin LDS insert cap
#define INS_STRIDE 25   // LDS row stride (gcd(25,32)=1 -> bank spread)

#if defined(__has_builtin)
#if __has_builtin(__builtin_amdgcn_cvt_pk_f32_fp8) && __has_builtin(__builtin_amdgcn_cvt_pk_fp8_f32)
#define HAS_CVT_FP8 1
#endif
#endif

typedef float v2f_t __attribute__((ext_vector_type(2)));

__device__ inline float fp8_dec_byte(int b) {
    int s = (b >> 7) & 1, e = (b >> 3) & 15, m = b & 7;
    float v = (e == 0) ? ldexpf((float)m, -9) : ldexpf((float)(8 + m), e - 10);
    return s ? -v : v;
}
__device__ inline unsigned int fp8_enc(float x) {
    unsigned int u = __float_as_uint(x);
    unsigned int s = u >> 31;
    u &= 0x7fffffffu;
    float a = __uint_as_float(u);
    unsigned int code;
    if (a >= 0.015625f) {
        if (a > 448.0f) code = 0x7E;
        else {
            int exp = (int)(u >> 23) - 127;
            unsigned int mant = u & 0x7fffffu;
            unsigned int keep = mant >> 20;
            unsigned int rest = mant & 0xfffffu;
            code = ((unsigned int)(exp + 7) << 3) | keep;
            unsigned int rnd = (rest > 0x80000u) || (rest == 0x80000u && (code & 1));
            code += rnd;
            if (code > 0x7E) code = 0x7E;
        }
    } else {
        code = (unsigned int)(a * 512.0f + 0.5f);
    }
    return (s << 7) | code;
}

// ---------------- setup: zero tails + graph bounds + BN fold ----------------
__global__ void setup_kernel(int* __restrict__ tails, int ntail,
                             const int* __restrict__ batch, int* __restrict__ gstart,
                             int n, int g,
                             const float* __restrict__ conv0_b, const float* __restrict__ convs_b,
                             const float* __restrict__ gamma, const float* __restrict__ beta,
                             const float* __restrict__ mean, const float* __restrict__ var,
                             float* __restrict__ sc, float* __restrict__ sh) {
    int i = blockIdx.x * 256 + threadIdx.x;
    if (i < ntail * 32) tails[i] = 0;
    if (i < 384) {
        int l = i >> 7, f = i & 127;
        float bias = (l == 0) ? conv0_b[f] : convs_b[(l - 1) * 128 + f];
        float s = gamma[i] * rsqrtf(var[i] + EPSBN);
        sc[i] = s;
        sh[i] = fmaf(s, bias - mean[i], beta[i]);
    }
    if (i < n) {
        int b = batch[i];
        int bp = (i == 0) ? -1 : batch[i - 1];
        for (int q = bp + 1; q <= b; ++q) gstart[q] = i;
        if (i == n - 1) {
            for (int q = b + 1; q <= g; ++q) gstart[q] = n;
        }
    }
}

// ---------------- bucket edges by dst window (d>>8) via LDS staging ----------------
__launch_bounds__(256)
__global__ void bucket_kernel(const int* __restrict__ src, const int* __restrict__ dst,
                              unsigned int* __restrict__ buckets, int* __restrict__ tails,
                              unsigned int* __restrict__ ovf, int e, int nwq) {
    __shared__ unsigned int buf[256 * INS_STRIDE];
    __shared__ int cnt[256];
    __shared__ int basee[256];
    int t = threadIdx.x;
    cnt[t] = 0;
    __syncthreads();
    int c0 = blockIdx.x * 2048;
    int c1 = min(c0 + 2048, e);
    for (int i = c0 + t; i < c1; i += 256) {
        int d = dst[i];
        int bb = d >> 8;
        unsigned int val = (unsigned int)src[i] | ((unsigned int)d << 16);
        int pos = atomicAdd(&cnt[bb], 1);
        if (pos < INS_CAP) buf[bb * INS_STRIDE + pos] = val;
        else {
            int op = atomicAdd(&tails[nwq * 32], 1);
            if (op < OVCAP) ovf[op] = val;
        }
    }
    __syncthreads();
    int lane = t & 63, wv = t >> 6;
    int bb0 = wv * 64;
    {
        int b = bb0 + lane;
        int c = (b < nwq) ? min(cnt[b], INS_CAP) : 0;
        basee[b] = c ? atomicAdd(&tails[b * 32], c) : 0;
    }
    for (int k = 0; k < 64; ++k) {
        int b = bb0 + k;
        if (b >= nwq) break;
        int c = min(cnt[b], INS_CAP);
        if (c == 0) continue;
        int g = basee[b];
        if (lane < c) {
            unsigned int v = buf[b * INS_STRIDE + lane];
            int gp = g + lane;
            if (gp < BCAP) buckets[(size_t)b * BCAP + gp] = v;
            else {
                int op = atomicAdd(&tails[nwq * 32], 1);
                if (op < OVCAP) ovf[op] = v;
            }
        }
    }
}

// ---------------- build CSR window-locally in LDS; coalesced write-out ----------------
__launch_bounds__(256)
__global__ void build_csr(const unsigned int* __restrict__ buckets,
                          const int* __restrict__ tails, const unsigned int* __restrict__ ovf,
                          unsigned short* __restrict__ csr, int* __restrict__ deg,
                          int* __restrict__ offs, float* __restrict__ dinv,
                          int n, int nwq) {
    __shared__ unsigned short csrL[CSRL_CAP];
    __shared__ int degL[256], curL[256], offsL[256], cntW[256];
    __shared__ int wsum4[4];
    __shared__ int wstart;
    int b = blockIdx.x, t = threadIdx.x;
    int lo = b << 8;
    int hi = min(lo + 256, n);
    int nw = hi - lo;
    int ovn = min(tails[nwq * 32], OVCAP);
    cntW[t] = (t < nwq) ? min(tails[t * 32], BCAP) : 0;
    degL[t] = 0;
    __syncthreads();
    for (int i = t; i < ovn; i += 256)
        atomicAdd(&cntW[(ovf[i] >> 16) >> 8], 1);
    __syncthreads();
    if (t == 0) {
        int s = 0;
        for (int w = 0; w < b; ++w) s += cntW[w];
        wstart = s;
    }
    int myvalid = min(tails[b * 32], BCAP);
    const unsigned int* myb = buckets + (size_t)b * BCAP;
    for (int i = t; i < myvalid; i += 256)
        atomicAdd(&degL[(myb[i] >> 16) & 255], 1);
    for (int i = t; i < ovn; i += 256) {
        unsigned int v = ovf[i];
        int d = v >> 16;
        if (d >= lo && d < hi) atomicAdd(&degL[d & 255], 1);
    }
    __syncthreads();
    {
        int lane = t & 63, wv = t >> 6;
        int v = degL[t];
        int sc = v;
        #pragma unroll
        for (int o = 1; o < 64; o <<= 1) {
            int u = __shfl_up(sc, o);
            if (lane >= o) sc += u;
        }
        if (lane == 63) wsum4[wv] = sc;
        __syncthreads();
        int wb = 0;
        for (int q = 0; q < wv; ++q) wb += wsum4[q];
        offsL[t] = wb + sc - v;
        curL[t] = offsL[t];
    }
    __syncthreads();
    for (int i = t; i < myvalid; i += 256) {
        unsigned int v = myb[i];
        int pos = atomicAdd(&curL[(v >> 16) & 255], 1);
        if (pos < CSRL_CAP) csrL[pos] = (unsigned short)(v & 0xffffu);
    }
    for (int i = t; i < ovn; i += 256) {
        unsigned int v = ovf[i];
        int d = v >> 16;
        if (d >= lo && d < hi) {
            int pos = atomicAdd(&curL[d & 255], 1);
            if (pos < CSRL_CAP) csrL[pos] = (unsigned short)(v & 0xffffu);
        }
    }
    __syncthreads();
    int base = wstart;
    int total = min(cntW[b], CSRL_CAP);
    for (int i = t; i < total; i += 256)
        csr[base + i] = csrL[i];
    if (t < nw) {
        int dgi = degL[t];
        deg[lo + t] = dgi;
        offs[lo + t] = base + offsL[t];
        dinv[lo + t] = rsqrtf((float)dgi + 1.0f);
    }
}

// ---------------- fused layer-0: agg(x) 7-dim + dense 7->128 + BN + relu ----------------
__launch_bounds__(256)
__global__ void layer0_kernel(const float* __restrict__ x, const unsigned short* __restrict__ csr,
                              const int* __restrict__ offs, const int* __restrict__ degi,
                              const float* __restrict__ dinv, const float* __restrict__ W,
                              const float* __restrict__ sc, const float* __restrict__ sh,
                              float* __restrict__ out, int n) {
    __shared__ float sW[7 * 128];
    __shared__ float ssc[128], ssh[128];
    int t = threadIdx.x;
    for (int i = t; i < 7 * 128; i += 256) sW[i] = W[i];
    if (t < 128) { ssc[t] = sc[t]; ssh[t] = sh[t]; }
    __syncthreads();
    int lane = t & 63;
    int node = blockIdx.x * 4 + (t >> 6);
    if (node >= n) return;
    int e = lane >> 3, f = lane & 7;
    int off = offs[node], cnt = degi[node];
    float di = dinv[node];
    float acc = 0.f, accB = 0.f;
    for (int b0 = 0; b0 < cnt; b0 += 64) {
        int j = b0 + lane;
        int s = 0; float dv = 0.f;
        if (j < cnt) { s = csr[off + j]; dv = dinv[s]; }
        int m = cnt - b0; if (m > 64) m = 64;
        int m16 = (m + 15) & ~15;
        for (int i2 = 0; i2 < m16; i2 += 16) {
            int ss1 = __shfl(s, i2 + e);
            int ss2 = __shfl(s, i2 + 8 + e);
            float d1 = __shfl(dv, i2 + e);
            float d2 = __shfl(dv, i2 + 8 + e);
            float v1 = 0.f, v2 = 0.f;
            if (f < 7) {
                v1 = d1 * x[(size_t)ss1 * 7 + f];
                v2 = d2 * x[(size_t)ss2 * 7 + f];
            }
            acc += v1; accB += v2;
        }
    }
    acc += accB;
    acc += __shfl_xor(acc, 8);
    acc += __shfl_xor(acc, 16);
    acc += __shfl_xor(acc, 32);
    float self = (f < 7) ? x[(size_t)node * 7 + f] : 0.f;
    float xa = di * (acc + di * self);
    float xk[7];
    #pragma unroll
    for (int k = 0; k < 7; ++k) xk[k] = __shfl(xa, k);
    int fo = lane * 2;
    float o0 = 0.f, o1 = 0.f;
    #pragma unroll
    for (int k = 0; k < 7; ++k) {
        o0 = fmaf(xk[k], sW[k * 128 + fo], o0);
        o1 = fmaf(xk[k], sW[k * 128 + fo + 1], o1);
    }
    o0 = fmaxf(fmaf(ssc[fo],     o0, ssh[fo]),     0.f);
    o1 = fmaxf(fmaf(ssc[fo + 1], o1, ssh[fo + 1]), 0.f);
    *(float2*)(out + (size_t)node * 128 + fo) = make_float2(o0, o1);
}

// ---------------- 128x128 GEMM fp32 -> fp8 e4m3 output ----------------
__launch_bounds__(256)
__global__ void gemm128_fp8(const float* __restrict__ h, const float* __restrict__ W,
                            unsigned char* __restrict__ out, int n) {
    __shared__ float sh[64 * 132];
    int t = threadIdx.x;
    int row0 = blockIdx.x * 64;
    int rows = n - row0; if (rows > 64) rows = 64;

    for (int idx4 = t * 4; idx4 < 64 * 128; idx4 += 1024) {
        int r = idx4 >> 7, k = idx4 & 127;
        float4 v;
        if (r < rows) v = *(const float4*)(h + (size_t)(row0 + r) * 128 + k);
        else          v = make_float4(0.f, 0.f, 0.f, 0.f);
        *(float4*)(&sh[r * 132 + k]) = v;
    }
    __syncthreads();

    int f0 = (t & 15) * 8;
    int r0 = (t >> 4) * 4;
    float acc[4][8];
    #pragma unroll
    for (int i = 0; i < 4; ++i)
        #pragma unroll
        for (int c = 0; c < 8; ++c) acc[i][c] = 0.f;

    for (int k0 = 0; k0 < 128; k0 += 4) {
        float a_s[4][4];
        #pragma unroll
        for (int i = 0; i < 4; ++i) {
            float4 v = *(const float4*)(&sh[(r0 + i) * 132 + k0]);
            a_s[i][0] = v.x; a_s[i][1] = v.y; a_s[i][2] = v.z; a_s[i][3] = v.w;
        }
        float w_s[4][8];
        #pragma unroll
        for (int j = 0; j < 4; ++j) {
            float4 w0 = *(const float4*)(W + (size_t)(k0 + j) * 128 + f0);
            float4 w1 = *(const float4*)(W + (size_t)(k0 + j) * 128 + f0 + 4);
            w_s[j][0] = w0.x; w_s[j][1] = w0.y; w_s[j][2] = w0.z; w_s[j][3] = w0.w;
            w_s[j][4] = w1.x; w_s[j][5] = w1.y; w_s[j][6] = w1.z; w_s[j][7] = w1.w;
        }
        #pragma unroll
        for (int j = 0; j < 4; ++j)
            #pragma unroll
            for (int i = 0; i < 4; ++i)
                #pragma unroll
                for (int c = 0; c < 8; ++c)
                    acc[i][c] = fmaf(a_s[i][j], w_s[j][c], acc[i][c]);
    }

    #pragma unroll
    for (int i = 0; i < 4; ++i) {
        if (r0 + i < rows) {
            unsigned int q0, q1;
#ifdef HAS_CVT_FP8
            int p = __builtin_amdgcn_cvt_pk_fp8_f32(acc[i][0], acc[i][1], 0, false);
            p = __builtin_amdgcn_cvt_pk_fp8_f32(acc[i][2], acc[i][3], p, true);
            q0 = (unsigned int)p;
            int p2 = __builtin_amdgcn_cvt_pk_fp8_f32(acc[i][4], acc[i][5], 0, false);
            p2 = __builtin_amdgcn_cvt_pk_fp8_f32(acc[i][6], acc[i][7], p2, true);
            q1 = (unsigned int)p2;
#else
            q0 = fp8_enc(acc[i][0]) | (fp8_enc(acc[i][1]) << 8) |
                 (fp8_enc(acc[i][2]) << 16) | (fp8_enc(acc[i][3]) << 24);
            q1 = fp8_enc(acc[i][4]) | (fp8_enc(acc[i][5]) << 8) |
                 (fp8_enc(acc[i][6]) << 16) | (fp8_enc(acc[i][7]) << 24);
#endif
            uint2 o; o.x = q0; o.y = q1;
            *(uint2*)(out + (size_t)(row0 + r0 + i) * 128 + f0) = o;
        }
    }
}

// ---------------- aggregation over fp8 table + foldedBN + ReLU ----------------
__launch_bounds__(256)
__global__ void agg_fp8(const unsigned int* __restrict__ hw, const unsigned short* __restrict__ csr,
                        const int* __restrict__ offs, const int* __restrict__ degi,
                        const float* __restrict__ dinv,
                        const float* __restrict__ sc, const float* __restrict__ shv,
                        float* __restrict__ out, int n) {
#ifndef HAS_CVT_FP8
    __shared__ float lut[256];
    if (threadIdx.x < 256) lut[threadIdx.x] = fp8_dec_byte(threadIdx.x);
    __syncthreads();
#endif
    int lane = threadIdx.x & 63;
    int node = blockIdx.x * 4 + (threadIdx.x >> 6);
    if (node >= n) return;
    int fl = lane & 31, half = lane >> 5;
    float di = dinv[node];
    float a0 = 0.f, a1 = 0.f, a2 = 0.f, a3 = 0.f;
    int off = offs[node], cnt = degi[node];

    for (int b0 = 0; b0 < cnt; b0 += 64) {
        int j = b0 + lane;
        int s = 0; float dv = 0.f;
        if (j < cnt) { s = csr[off + j]; dv = dinv[s]; }
        int m = cnt - b0; if (m > 64) m = 64;
        int m16 = (m + 15) & ~15;
        for (int e = 0; e < m16; e += 16) {
            unsigned int w[8]; float nn[8];
            #pragma unroll
            for (int u = 0; u < 8; ++u) {
                int jj = e + u * 2 + half;
                int ss = __shfl(s, jj);
                nn[u] = __shfl(dv, jj);
                w[u] = hw[(size_t)ss * 32 + fl];
            }
            #pragma unroll
            for (int u = 0; u < 8; ++u) {
#ifdef HAS_CVT_FP8
                v2f_t lo = __builtin_amdgcn_cvt_pk_f32_fp8((int)w[u], false);
                v2f_t hi = __builtin_amdgcn_cvt_pk_f32_fp8((int)w[u], true);
                a0 = fmaf(nn[u], lo[0], a0);
                a1 = fmaf(nn[u], lo[1], a1);
                a2 = fmaf(nn[u], hi[0], a2);
                a3 = fmaf(nn[u], hi[1], a3);
#else
                a0 = fmaf(nn[u], lut[w[u] & 255], a0);
                a1 = fmaf(nn[u], lut[(w[u] >> 8) & 255], a1);
                a2 = fmaf(nn[u], lut[(w[u] >> 16) & 255], a2);
                a3 = fmaf(nn[u], lut[w[u] >> 24], a3);
#endif
            }
        }
    }
    a0 += __shfl_xor(a0, 32);
    a1 += __shfl_xor(a1, 32);
    a2 += __shfl_xor(a2, 32);
    a3 += __shfl_xor(a3, 32);
    if (half == 0) {
        int f0 = fl * 4;
        unsigned int ws = hw[(size_t)node * 32 + fl];
        float s0, s1, s2, s3;
#ifdef HAS_CVT_FP8
        v2f_t lo = __builtin_amdgcn_cvt_pk_f32_fp8((int)ws, false);
        v2f_t hi = __builtin_amdgcn_cvt_pk_f32_fp8((int)ws, true);
        s0 = lo[0]; s1 = lo[1]; s2 = hi[0]; s3 = hi[1];
#else
        s0 = lut[ws & 255]; s1 = lut[(ws >> 8) & 255];
        s2 = lut[(ws >> 16) & 255]; s3 = lut[ws >> 24];
#endif
        a0 = (a0 + di * s0) * di;
        a1 = (a1 + di * s1) * di;
        a2 = (a2 + di * s2) * di;
        a3 = (a3 + di * s3) * di;
        float4 o;
        o.x = fmaxf(fmaf(sc[f0],     a0, shv[f0]),     0.f);
        o.y = fmaxf(fmaf(sc[f0 + 1], a1, shv[f0 + 1]), 0.f);
        o.z = fmaxf(fmaf(sc[f0 + 2], a2, shv[f0 + 2]), 0.f);
        o.w = fmaxf(fmaf(sc[f0 + 3], a3, shv[f0 + 3]), 0.f);
        *(float4*)(out + (size_t)node * 128 + f0) = o;
    }
}

// ---------------- pocket MLP + fold bilinear ----------------
__global__ void pk_bilM_kernel(const float* __restrict__ pf, const float* __restrict__ W1,
                               const float* __restrict__ b1, const float* __restrict__ W2,
                               const float* __restrict__ b2, const float* __restrict__ bilW,
                               float* __restrict__ M) {
    __shared__ float h1[64];
    __shared__ float spk[64];
    int t = threadIdx.x;
    if (t < 64) {
        float acc = b1[t];
        #pragma unroll
        for (int k = 0; k < 28; ++k) acc = fmaf(pf[k], W1[k * 64 + t], acc);
        h1[t] = fmaxf(acc, 0.f);
    }
    __syncthreads();
    if (t < 64) {
        float acc2 = b2[t];
        for (int k = 0; k < 64; ++k) acc2 = fmaf(h1[k], W2[k * 64 + t], acc2);
        spk[t] = acc2;
    }
    __syncthreads();
    int idx = blockIdx.x * 256 + t;
    if (idx < 64 * 128) {
        const float* wr = bilW + (size_t)idx * 64;
        float acc = 0.f;
        #pragma unroll 8
        for (int j = 0; j < 64; ++j) acc = fmaf(wr[j], spk[j], acc);
        M[idx] = acc;
    }
}

// ---------------- per-graph tail (fused segment-mean + bilinear + classifier) ----------------
__launch_bounds__(128)
__global__ void final_kernel(const float* __restrict__ h, const int* __restrict__ gstart,
                             const float* __restrict__ M, const float* __restrict__ bil_b,
                             const float* __restrict__ cW1, const float* __restrict__ cb1,
                             const float* __restrict__ cW2, const float* __restrict__ cb2,
                             float* __restrict__ out) {
    __shared__ float lig[128];
    __shared__ float inter[64];
    __shared__ float hc[32];
    int g = blockIdx.x, t = threadIdx.x;
    int s = gstart[g], e = gstart[g + 1];
    float a0 = 0.f, a1 = 0.f, a2 = 0.f, a3 = 0.f;
    int i = s;
    for (; i + 4 <= e; i += 4) {
        a0 += h[(size_t)(i + 0) * 128 + t];
        a1 += h[(size_t)(i + 1) * 128 + t];
        a2 += h[(size_t)(i + 2) * 128 + t];
        a3 += h[(size_t)(i + 3) * 128 + t];
    }
    for (; i < e; ++i) a0 += h[(size_t)i * 128 + t];
    float c = (float)(e - s); if (c < 1.f) c = 1.f;
    lig[t] = ((a0 + a1) + (a2 + a3)) / c;
    __syncthreads();
    if (t < 64) {
        float acc = bil_b[t];
        const float* mr = M + (size_t)t * 128;
        #pragma unroll 8
        for (int k = 0; k < 128; ++k) acc = fmaf(lig[k], mr[k], acc);
        inter[t] = acc;
    }
    __syncthreads();
    if (t < 32) {
        float acc = cb1[t];
        #pragma unroll 8
        for (int o = 0; o < 64; ++o) acc = fmaf(inter[o], cW1[o * 32 + t], acc);
        hc[t] = fmaxf(acc, 0.f);
    }
    __syncthreads();
    if (t == 0) {
        float acc = cb2[0];
        #pragma unroll
        for (int j = 0; j < 32; ++j) acc = fmaf(hc[j], cW2[j], acc);
        out[g] = acc;
    }
}

extern "C" void kernel_launch(void* const* d_in, const int* in_sizes, int n_in,
                              void* d_out, int out_size, void* d_ws, size_t ws_size,
                              hipStream_t stream) {
    const float* x        = (const float*)d_in[0];
    const int*   edge     = (const int*)d_in[1];
    const int*   batch    = (const int*)d_in[2];
    const float* pocket   = (const float*)d_in[3];
    const float* conv0_W  = (const float*)d_in[4];
    const float* conv0_b  = (const float*)d_in[5];
    const float* convs_W  = (const float*)d_in[6];
    const float* convs_b  = (const float*)d_in[7];
    const float* bn_gamma = (const float*)d_in[8];
    const float* bn_beta  = (const float*)d_in[9];
    const float* bn_mean  = (const float*)d_in[10];
    const float* bn_var   = (const float*)d_in[11];
    const float* pmlp_W1  = (const float*)d_in[12];
    const float* pmlp_b1  = (const float*)d_in[13];
    const float* pmlp_W2  = (const float*)d_in[14];
    const float* pmlp_b2  = (const float*)d_in[15];
    const float* bil_W    = (const float*)d_in[16];
    const float* bil_b    = (const float*)d_in[17];
    const float* cls_W1   = (const float*)d_in[18];
    const float* cls_b1   = (const float*)d_in[19];
    const float* cls_W2   = (const float*)d_in[20];
    const float* cls_b2   = (const float*)d_in[21];

    const int N = in_sizes[0] / 7;
    const int E = in_sizes[1] / 2;
    const int G = out_size;
    const int* srcA = edge;
    const int* dstA = edge + E;
    const int NB = (N + 255) / 256;
    const int NWQ = (N + 255) >> 8;

    char* p = (char*)d_ws;
    auto alloc = [&](size_t bytes) -> void* {
        void* r = (void*)p;
        p += (bytes + 255) & ~(size_t)255;
        return r;
    };
    int*   tails    = (int*)alloc((size_t)(NWQ + 1) * 32 * 4);
    unsigned int* buckets = (unsigned int*)alloc((size_t)NWQ * BCAP * 4);
    unsigned int* ovf     = (unsigned int*)alloc((size_t)OVCAP * 4);
    int*   deg      = (int*)alloc((size_t)N * 4);
    int*   offs     = (int*)alloc((size_t)N * 4);
    float* dinv     = (float*)alloc((size_t)N * 4);
    unsigned short* csr = (unsigned short*)alloc((size_t)E * 2);
    unsigned char* bufH8 = (unsigned char*)alloc((size_t)N * 128);
    float* bufF     = (float*)alloc((size_t)N * 128 * 4);
    int*   gstart   = (int*)alloc((size_t)(G + 1) * 4);
    float* M        = (float*)alloc(64 * 128 * 4);
    float* sc       = (float*)alloc(384 * 4);
    float* shv      = (float*)alloc(384 * 4);

    setup_kernel<<<NB, 256, 0, stream>>>(tails, NWQ + 1, batch, gstart, N, G,
                                         conv0_b, convs_b, bn_gamma, bn_beta, bn_mean, bn_var,
                                         sc, shv);
    bucket_kernel<<<(E + 2047) / 2048, 256, 0, stream>>>(srcA, dstA, buckets, tails, ovf,
                                                         E, NWQ);
    build_csr<<<NWQ, 256, 0, stream>>>(buckets, tails, ovf, csr, deg, offs, dinv, N, NWQ);

    // layer 0 (fused agg + dense + BN + relu)
    layer0_kernel<<<(N + 3) / 4, 256, 0, stream>>>(x, csr, offs, deg, dinv, conv0_W,
                                                   sc, shv, bufF, N);
    // layer 1
    gemm128_fp8<<<(N + 63) / 64, 256, 0, stream>>>(bufF, convs_W, bufH8, N);
    agg_fp8<<<(N + 3) / 4, 256, 0, stream>>>((const unsigned int*)bufH8, csr, offs, deg, dinv,
                                             sc + 128, shv + 128, bufF, N);
    // layer 2
    gemm128_fp8<<<(N + 63) / 64, 256, 0, stream>>>(bufF, convs_W + 128 * 128, bufH8, N);
    agg_fp8<<<(N + 3) / 4, 256, 0, stream>>>((const unsigned int*)bufH8, csr, offs, deg, dinv,
                                             sc + 256, shv + 256, bufF, N);

    pk_bilM_kernel<<<32, 256, 0, stream>>>(pocket, pmlp_W1, pmlp_b1, pmlp_W2, pmlp_b2,
                                           bil_W, M);
    final_kernel<<<G, 128, 0, stream>>>(bufF, gstart, M, bil_b, cls_W1, cls_b1, cls_W2, cls_b2,
                                        (float*)d_out);
}